// Round 24
// baseline (228.165 us; speedup 1.0000x reference)
//
#include <hip/hip_runtime.h>
#include <hip/hip_fp16.h>

// Problem constants (match reference file)
#define NN 100000
#define NE 1600000
#define NG 64

// Two-level-v2 CSR build:
//  - bin scatters into COARSE 1024-node buckets (long write runs, ~1.7x write amp;
//    kernel correctness-proven in R18, where WRITE measured 9.2 MB).
//  - build_csr processes ONE WHOLE coarse bucket per 1024-thread block (98 blocks),
//    so each binned entry is read exactly twice (hist+place) -- fixes R18's 8x read-amp.
#define BSHIFT_C 10
#define BUCKW_C (1 << BSHIFT_C)                   // 1024 nodes per coarse bucket
#define NBUCK_C ((NN + BUCKW_C - 1) >> BSHIFT_C)  // 98
#define BCAP_C 18432                              // mean 16384, sigma~127 -> 16 sigma
#define BIN_CHUNK 2048                            // 782 bin blocks; 8 edges/thread reg-cached

// ---- fp16 helpers (activations stored fp16, math in fp32) ----
union H8 { float4 f4; __half2 h2[4]; };
union H4 { float2 f2; __half2 h2[2]; };
__device__ __forceinline__ void h8_to_f(const H8& h, float* f) {
    float2 a = __half22float2(h.h2[0]);
    float2 b = __half22float2(h.h2[1]);
    float2 c = __half22float2(h.h2[2]);
    float2 d = __half22float2(h.h2[3]);
    f[0]=a.x; f[1]=a.y; f[2]=b.x; f[3]=b.y; f[4]=c.x; f[5]=c.y; f[6]=d.x; f[7]=d.y;
}
__device__ __forceinline__ H8 f_to_h8(const float* f) {
    H8 h;
    h.h2[0] = __floats2half2_rn(f[0], f[1]);
    h.h2[1] = __floats2half2_rn(f[2], f[3]);
    h.h2[2] = __floats2half2_rn(f[4], f[5]);
    h.h2[3] = __floats2half2_rn(f[6], f[7]);
    return h;
}
__device__ __forceinline__ float prelu_f(float x, float s) {
    return fmaxf(x, 0.f) + s * fminf(x, 0.f);
}

// ---------------- bin edges by COARSE dst-bucket (R18-verified kernel) ----------------
// binned layout: coarse bucket cb owns [cb*BCAP_C, cb*BCAP_C + cnt[cb]);
// packed entry = (src<<10) | (dst & 1023). bcnt (zeroed) is the per-bucket cursor.
__global__ __launch_bounds__(256) void bin_kernel(const int* __restrict__ src,
                                                  const int* __restrict__ dst,
                                                  int* __restrict__ bcnt,
                                                  unsigned* __restrict__ binned, int E) {
    __shared__ int h[NBUCK_C];
    __shared__ int cur[NBUCK_C];
    int tid = threadIdx.x;
    for (int i = tid; i < NBUCK_C; i += 256) h[i] = 0;
    __syncthreads();
    int base = blockIdx.x * BIN_CHUNK;
    int end = base + BIN_CHUNK; if (end > E) end = E;
    int ms[8], md[8];
#pragma unroll
    for (int k = 0; k < 8; ++k) {
        int e = base + k * 256 + tid;
        if (e < end) { ms[k] = src[e]; md[k] = dst[e]; }
    }
#pragma unroll
    for (int k = 0; k < 8; ++k) {
        int e = base + k * 256 + tid;
        if (e < end) atomicAdd(&h[md[k] >> BSHIFT_C], 1);
    }
    __syncthreads();
    for (int i = tid; i < NBUCK_C; i += 256) {
        int c = h[i];
        cur[i] = c ? (i * BCAP_C + atomicAdd(&bcnt[i], c)) : 0;  // reserve contiguous sub-range
    }
    __syncthreads();
#pragma unroll
    for (int k = 0; k < 8; ++k) {
        int e = base + k * 256 + tid;
        if (e < end) {
            unsigned s = (unsigned)ms[k], d = (unsigned)md[k];
            int pos = atomicAdd(&cur[d >> BSHIFT_C], 1);
            binned[pos] = (s << BSHIFT_C) | (d & (BUCKW_C - 1));
        }
    }
}

// ==== CSR tail over a WHOLE coarse bucket: deg + dinv + xs + roff + placement =========
// One 1024-thread block per coarse bucket (98 blocks). Each binned entry is read twice.
// roff[v] = cb*BCAP_C + prefix(deg within bucket) -- downstream layout-agnostic.
__global__ __launch_bounds__(1024) void build_csr_kernel(
    const unsigned* __restrict__ binned, const int* __restrict__ bucket_cnt,
    const float4* __restrict__ x4, float4* __restrict__ xs,
    int* __restrict__ deg, float* __restrict__ dinv,
    int* __restrict__ roff, int* __restrict__ csr_src, int n) {
    __shared__ int ldeg[BUCKW_C];       // 4 KB
    __shared__ int lscan[2][BUCKW_C];   // 8 KB
    __shared__ int lcur[BUCKW_C];       // 4 KB
    int cb = blockIdx.x;
    int tid = threadIdx.x;              // 0..1023, covers BUCKW_C exactly
    ldeg[tid] = 0;
    __syncthreads();
    int start = cb * BCAP_C, cnt = bucket_cnt[cb];
    for (int k = tid; k < cnt; k += 1024)
        atomicAdd(&ldeg[binned[start + k] & (BUCKW_C - 1)], 1);
    __syncthreads();
    lscan[0][tid] = ldeg[tid];
    __syncthreads();
    int cur = 0;
    for (int off = 1; off < BUCKW_C; off <<= 1) {
        int x = lscan[cur][tid];
        if (tid >= off) x += lscan[cur][tid - off];
        __syncthreads();
        lscan[cur ^ 1][tid] = x;
        __syncthreads();
        cur ^= 1;
    }
    int v = (cb << BSHIFT_C) + tid;
    if (v < n) {
        int dg = ldeg[tid];
        deg[v] = dg;
        float dv = rsqrtf((float)dg + 1.0f);  // +1 = self loop
        dinv[v] = dv;
        float4 h0 = x4[(size_t)v * 2 + 0];
        float4 h1 = x4[(size_t)v * 2 + 1];
        h0.x *= dv; h0.y *= dv; h0.z *= dv; h0.w *= dv;
        h1.x *= dv; h1.y *= dv; h1.z *= dv; h1.w *= dv;
        xs[(size_t)v * 2 + 0] = h0;
        xs[(size_t)v * 2 + 1] = h1;
        int r = start + lscan[cur][tid] - dg; // bucket-local exclusive prefix
        roff[v] = r;
        lcur[tid] = r;
    }
    __syncthreads();
    for (int k = tid; k < cnt; k += 1024) {
        unsigned e = binned[start + k];
        int pos = atomicAdd(&lcur[e & (BUCKW_C - 1)], 1);
        csr_src[pos] = (int)(e >> BSHIFT_C);
    }
}

// ---------------- makeM: M = W4 @ Wlin (64x4), bb = b4 @ Wlin + blin ----------------
__global__ __launch_bounds__(256) void makeM_kernel(
    const float* __restrict__ W4, const float* __restrict__ b4,
    const float* __restrict__ Wlin, const float* __restrict__ blin,
    float* __restrict__ M, float* __restrict__ bb) {
    int t = threadIdx.x;          // 256 = 64 * 4
    int k = t >> 2, c = t & 3;
    float m = 0.f;
    for (int j = 0; j < 128; ++j) m += W4[k * 128 + j] * Wlin[j * 4 + c];
    M[k * 4 + c] = m;
    if (t < 4) {
        float v = blin[t];
        for (int j = 0; j < 128; ++j) v += b4[j] * Wlin[j * 4 + t];
        bb[t] = v;
    }
}

// ======== LAYER 1 fused: agg(prescaled xs, neighbor-split x2) + matmul(8->16) =========
__global__ __launch_bounds__(256) void aggmm1_kernel(
    const float4* __restrict__ xs, const int* __restrict__ row_off,
    const int* __restrict__ deg, const float* __restrict__ dinv,
    const int* __restrict__ csr_src, const float* __restrict__ W1,
    const float* __restrict__ b1, const float* __restrict__ a1,
    float2* __restrict__ Aout2, int n) {
    __shared__ float Wl[8 * 16];
    for (int i = threadIdx.x; i < 8 * 16; i += 256) Wl[i] = W1[i];
    __syncthreads();
    int idx = blockIdx.x * 256 + threadIdx.x;
    if (idx >= n * 4) return;                 // 4-lane groups aligned
    int v = idx >> 2;
    int c = idx & 1;
    int h = (idx >> 1) & 1;
    float4 acc = (h == 0) ? xs[(size_t)v * 2 + c] : make_float4(0.f, 0.f, 0.f, 0.f);
    int start = row_off[v], cnt = deg[v];
    int mid = cnt >> 1;
    int beg = h ? mid : 0;
    int myend = h ? cnt : mid;
    const int* __restrict__ row = csr_src + start;
    int j = beg;
    for (; j + 4 <= myend; j += 4) {
        int s0 = row[j], s1 = row[j + 1], s2 = row[j + 2], s3 = row[j + 3];
        float4 a0 = xs[(size_t)s0 * 2 + c];
        float4 a1v = xs[(size_t)s1 * 2 + c];
        float4 a2 = xs[(size_t)s2 * 2 + c];
        float4 a3 = xs[(size_t)s3 * 2 + c];
        acc.x += (a0.x + a1v.x) + (a2.x + a3.x);
        acc.y += (a0.y + a1v.y) + (a2.y + a3.y);
        acc.z += (a0.z + a1v.z) + (a2.z + a3.z);
        acc.w += (a0.w + a1v.w) + (a2.w + a3.w);
    }
    for (; j < myend; ++j) {
        int s = row[j];
        float4 a = xs[(size_t)s * 2 + c];
        acc.x += a.x; acc.y += a.y; acc.z += a.z; acc.w += a.w;
    }
    acc.x += __shfl_xor(acc.x, 2, 64);        // combine h-halves
    acc.y += __shfl_xor(acc.y, 2, 64);
    acc.z += __shfl_xor(acc.z, 2, 64);
    acc.w += __shfl_xor(acc.w, 2, 64);
    float dvv = dinv[v];
    float t[4] = { acc.x * dvv, acc.y * dvv, acc.z * dvv, acc.w * dvv };
    float po[4];
#pragma unroll
    for (int k = 0; k < 4; ++k) po[k] = __shfl_xor(t[k], 1, 64);   // c-partner inputs
    int ow = (h * 2 + c) * 4;                 // this thread's 4-output block
    int e0 = c * 4, e1 = 4 - e0;
    float accm[4];
#pragma unroll
    for (int q = 0; q < 4; ++q) accm[q] = b1[ow + q];
#pragma unroll
    for (int k = 0; k < 4; ++k) {
        float r1 = t[k], r2 = po[k];
        const float* w1 = &Wl[(e0 + k) * 16 + ow];
        const float* w2 = &Wl[(e1 + k) * 16 + ow];
#pragma unroll
        for (int q = 0; q < 4; ++q) accm[q] += r1 * w1[q] + r2 * w2[q];
    }
    float s = *a1;
    float o[4];
#pragma unroll
    for (int q = 0; q < 4; ++q) o[q] = prelu_f(accm[q], s) * dvv;
    H4 ho;
    ho.h2[0] = __floats2half2_rn(o[0], o[1]);
    ho.h2[1] = __floats2half2_rn(o[2], o[3]);
    Aout2[(size_t)v * 4 + (h * 2 + c)] = ho.f2;   // A-row = 16 halfs = 4 float2s
}

// ======== LAYER 2 fused: agg(16, neighbor-split x2) + matmul(16->32) + prelu ==========
__global__ __launch_bounds__(256) void aggmm2_kernel(
    const float4* __restrict__ hs, const int* __restrict__ row_off,
    const int* __restrict__ deg, const float* __restrict__ dinv,
    const int* __restrict__ csr_src, const float* __restrict__ W2,
    const float* __restrict__ b2, const float* __restrict__ a2,
    float4* __restrict__ Aout, int n) {
    __shared__ float Wl[16 * 32];   // 2 KB
    for (int i = threadIdx.x; i < 16 * 32; i += 256) Wl[i] = W2[i];
    __syncthreads();
    int idx = blockIdx.x * 256 + threadIdx.x;
    if (idx >= n * 4) return;                 // 4-lane groups aligned: partners agree
    int v = idx >> 2;
    int c = idx & 1;
    int h = (idx >> 1) & 1;
    float a[8];
    if (h == 0) { H8 t; t.f4 = hs[(size_t)v * 2 + c]; h8_to_f(t, a); }
    else {
#pragma unroll
        for (int k = 0; k < 8; ++k) a[k] = 0.f;
    }
    int start = row_off[v], cnt = deg[v];
    int mid = cnt >> 1;
    int beg = h ? mid : 0;
    int myend = h ? cnt : mid;
    const int* __restrict__ row = csr_src + start;
    int j = beg;
    for (; j + 4 <= myend; j += 4) {
        H8 hh[4];
#pragma unroll
        for (int q = 0; q < 4; ++q) hh[q].f4 = hs[(size_t)row[j + q] * 2 + c];
#pragma unroll
        for (int q = 0; q < 4; ++q) {
            float f[8]; h8_to_f(hh[q], f);
#pragma unroll
            for (int k = 0; k < 8; ++k) a[k] += f[k];
        }
    }
    for (; j < myend; ++j) {
        H8 t; t.f4 = hs[(size_t)row[j] * 2 + c];
        float f[8]; h8_to_f(t, f);
#pragma unroll
        for (int k = 0; k < 8; ++k) a[k] += f[k];
    }
#pragma unroll
    for (int k = 0; k < 8; ++k) a[k] += __shfl_xor(a[k], 2, 64);   // combine h-halves
    float dvv = dinv[v];
#pragma unroll
    for (int k = 0; k < 8; ++k) a[k] *= dvv;
    float pa[8];
#pragma unroll
    for (int k = 0; k < 8; ++k) pa[k] = __shfl_xor(a[k], 1, 64);   // c-partner inputs
    int ow = (h * 2 + c) * 8;                 // this thread's 8-output block
    int e0 = c * 8, e1 = 8 - e0;
    float accm[8];
#pragma unroll
    for (int q = 0; q < 8; ++q) accm[q] = b2[ow + q];
#pragma unroll
    for (int k = 0; k < 8; ++k) {
        float r1 = a[k], r2 = pa[k];
        const float* w1 = &Wl[(e0 + k) * 32 + ow];
        const float* w2 = &Wl[(e1 + k) * 32 + ow];
#pragma unroll
        for (int q = 0; q < 8; ++q) accm[q] += r1 * w1[q] + r2 * w2[q];
    }
    float s = *a2;
    float o[8];
#pragma unroll
    for (int q = 0; q < 8; ++q) o[q] = prelu_f(accm[q], s) * dvv;
    H8 ho = f_to_h8(o);
    Aout[(size_t)v * 4 + (h * 2 + c)] = ho.f4;   // A-row = 32 halfs = 4 float4s
}

// ======== LAYER 3 fused: agg(32, neighbor-split x2) + matmul(32->64) + @M -> z ========
__global__ __launch_bounds__(256) void aggmm3_kernel(
    const float4* __restrict__ hs, const int* __restrict__ row_off,
    const int* __restrict__ deg, const float* __restrict__ dinv,
    const int* __restrict__ csr_src, const float* __restrict__ W3,
    const float* __restrict__ b3, const float* __restrict__ a3,
    const float* __restrict__ M, float4* __restrict__ z, int n) {
    __shared__ float Wl[32 * 64];   // 8 KB
    __shared__ float Ml[64 * 4];    // 1 KB
    for (int i = threadIdx.x; i < 32 * 64; i += 256) Wl[i] = W3[i];
    for (int i = threadIdx.x; i < 64 * 4; i += 256) Ml[i] = M[i];
    __syncthreads();
    int idx = blockIdx.x * 256 + threadIdx.x;
    if (idx >= n * 8) return;                 // 8-lane groups aligned
    int v = idx >> 3;
    int c = idx & 3;
    int h = (idx >> 2) & 1;
    float a[8];
    if (h == 0) { H8 t; t.f4 = hs[(size_t)v * 4 + c]; h8_to_f(t, a); }
    else {
#pragma unroll
        for (int k = 0; k < 8; ++k) a[k] = 0.f;
    }
    int start = row_off[v], cnt = deg[v];
    int mid = cnt >> 1;
    int beg = h ? mid : 0;
    int myend = h ? cnt : mid;
    const int* __restrict__ row = csr_src + start;
    int j = beg;
    for (; j + 4 <= myend; j += 4) {
        H8 hh[4];
#pragma unroll
        for (int q = 0; q < 4; ++q) hh[q].f4 = hs[(size_t)row[j + q] * 4 + c];
#pragma unroll
        for (int q = 0; q < 4; ++q) {
            float f[8]; h8_to_f(hh[q], f);
#pragma unroll
            for (int k = 0; k < 8; ++k) a[k] += f[k];
        }
    }
    for (; j < myend; ++j) {
        H8 t; t.f4 = hs[(size_t)row[j] * 4 + c];
        float f[8]; h8_to_f(t, f);
#pragma unroll
        for (int k = 0; k < 8; ++k) a[k] += f[k];
    }
#pragma unroll
    for (int k = 0; k < 8; ++k) a[k] += __shfl_xor(a[k], 4, 64);   // combine h-halves
    float dvv = dinv[v];
#pragma unroll
    for (int k = 0; k < 8; ++k) a[k] *= dvv;
    int ow = (h * 4 + c) * 8;                 // this thread's 8-output block
    float accm[8];
#pragma unroll
    for (int q = 0; q < 8; ++q) accm[q] = b3[ow + q];
#pragma unroll
    for (int m = 0; m < 4; ++m) {
        float cur[8];
        if (m == 0) {
#pragma unroll
            for (int k = 0; k < 8; ++k) cur[k] = a[k];
        } else {
#pragma unroll
            for (int k = 0; k < 8; ++k) cur[k] = __shfl_xor(a[k], m, 64);
        }
        int eb = (c ^ m) * 8;
#pragma unroll
        for (int k = 0; k < 8; ++k) {
            float rk = cur[k];
            const float* wp = &Wl[(eb + k) * 64 + ow];
#pragma unroll
            for (int q = 0; q < 8; ++q) accm[q] += rk * wp[q];
        }
    }
    float s = *a3;
    float px = 0.f, py = 0.f, pz = 0.f, pw = 0.f;
#pragma unroll
    for (int q = 0; q < 8; ++q) {
        float o = prelu_f(accm[q], s) * dvv;
        const float* mp = &Ml[(ow + q) * 4];
        px += o * mp[0]; py += o * mp[1]; pz += o * mp[2]; pw += o * mp[3];
    }
#pragma unroll
    for (int mask = 1; mask <= 4; mask <<= 1) {
        px += __shfl_xor(px, mask, 64);
        py += __shfl_xor(py, mask, 64);
        pz += __shfl_xor(pz, mask, 64);
        pw += __shfl_xor(pw, mask, 64);
    }
    if ((idx & 7) == 0) z[v] = make_float4(px, py, pz, pw);
}

// ===== layer-4 aggregation + pooling in z-space (neighbor-split x2, wave-reduced) =====
__global__ __launch_bounds__(256) void aggpool4_kernel(
    const float4* __restrict__ z, const int* __restrict__ row_off,
    const int* __restrict__ deg, const float* __restrict__ dinv,
    const int* __restrict__ csr_src, const int* __restrict__ batch,
    float* __restrict__ sums, float* __restrict__ cnt, int n) {
    __shared__ float lacc[NG * 4];
    __shared__ float lcnt[NG];
    int tid = threadIdx.x;
    if (tid < NG * 4) lacc[tid] = 0.f;
    if (tid < NG) lcnt[tid] = 0.f;
    __syncthreads();
    int idx = blockIdx.x * 256 + tid;
    bool valid = (idx < n * 2);
    int v = idx >> 1;
    int h = idx & 1;
    float cx = 0.f, cy = 0.f, cz = 0.f, cw = 0.f, rc = 0.f;
    int g = -1;
    if (valid) {
        float4 acc = (h == 0) ? z[v] : make_float4(0.f, 0.f, 0.f, 0.f);
        int start = row_off[v], dcnt = deg[v];
        int mid = dcnt >> 1;
        int beg = h ? mid : 0;
        int myend = h ? dcnt : mid;
        const int* __restrict__ row = csr_src + start;
        int j = beg;
        for (; j + 4 <= myend; j += 4) {
            float4 a0 = z[row[j]];
            float4 a1 = z[row[j + 1]];
            float4 a2 = z[row[j + 2]];
            float4 a3 = z[row[j + 3]];
            acc.x += (a0.x + a1.x) + (a2.x + a3.x);
            acc.y += (a0.y + a1.y) + (a2.y + a3.y);
            acc.z += (a0.z + a1.z) + (a2.z + a3.z);
            acc.w += (a0.w + a1.w) + (a2.w + a3.w);
        }
        for (; j < myend; ++j) {
            float4 a = z[row[j]];
            acc.x += a.x; acc.y += a.y; acc.z += a.z; acc.w += a.w;
        }
        cx = acc.x; cy = acc.y; cz = acc.z; cw = acc.w;
        g = batch[v];
    }
    cx += __shfl_xor(cx, 1, 64);              // combine h-halves (pairs aligned)
    cy += __shfl_xor(cy, 1, 64);
    cz += __shfl_xor(cz, 1, 64);
    cw += __shfl_xor(cw, 1, 64);
    if (valid) {
        float dv = dinv[v];
        cx *= dv; cy *= dv; cz *= dv; cw *= dv;
    }
    if (!valid || h == 1) { cx = cy = cz = cw = 0.f; rc = 0.f; }
    else rc = 1.f;
    int g0 = __shfl(g, 0, 64);
    if (__all(g == g0 || !valid)) {
#pragma unroll
        for (int mask = 32; mask >= 1; mask >>= 1) {
            cx += __shfl_xor(cx, mask, 64);
            cy += __shfl_xor(cy, mask, 64);
            cz += __shfl_xor(cz, mask, 64);
            cw += __shfl_xor(cw, mask, 64);
            rc += __shfl_xor(rc, mask, 64);
        }
        if ((tid & 63) == 0 && g0 >= 0) {
            float* lp = &lacc[g0 * 4];
            atomicAdd(lp + 0, cx); atomicAdd(lp + 1, cy);
            atomicAdd(lp + 2, cz); atomicAdd(lp + 3, cw);
            atomicAdd(&lcnt[g0], rc);
        }
    } else if (valid && h == 0) {
        float* lp = &lacc[g * 4];
        atomicAdd(lp + 0, cx); atomicAdd(lp + 1, cy);
        atomicAdd(lp + 2, cz); atomicAdd(lp + 3, cw);
        atomicAdd(&lcnt[g], 1.f);
    }
    __syncthreads();
    if (tid < NG * 4) {
        float val = lacc[tid];
        if (val != 0.f) atomicAdd(&sums[tid], val);
    }
    if (tid < NG) {
        float val = lcnt[tid];
        if (val != 0.f) atomicAdd(&cnt[tid], val);
    }
}

// ---------------- head: out[g][c] = sums[g][c]/cnt[g] + bb[c] ----------------
__global__ void head_kernel(const float* __restrict__ sums, const float* __restrict__ cnt,
                            const float* __restrict__ bb, float* __restrict__ out) {
    int t = threadIdx.x;          // 256 = 64 graphs * 4 classes
    int g = t >> 2, c = t & 3;
    out[t] = sums[t] / fmaxf(cnt[g], 1.f) + bb[c];
}

extern "C" void kernel_launch(void* const* d_in, const int* in_sizes, int n_in,
                              void* d_out, int out_size, void* d_ws, size_t ws_size,
                              hipStream_t stream) {
    const float* x    = (const float*)d_in[0];
    const int* esrc   = (const int*)d_in[1];
    const int* edst   = (const int*)d_in[2];
    const int* batch  = (const int*)d_in[3];
    const float* W1 = (const float*)d_in[4],  *b1 = (const float*)d_in[5];
    const float* W2 = (const float*)d_in[6],  *b2 = (const float*)d_in[7];
    const float* W3 = (const float*)d_in[8],  *b3 = (const float*)d_in[9];
    const float* W4 = (const float*)d_in[10], *b4 = (const float*)d_in[11];
    const float* a1 = (const float*)d_in[12];
    const float* a2 = (const float*)d_in[13];
    const float* a3 = (const float*)d_in[14];
    const float* Wlin = (const float*)d_in[15], *blin = (const float*)d_in[16];
    float* out = (float*)d_out;

    const int N = NN, E = NE;
    const int NBIN = (E + BIN_CHUNK - 1) / BIN_CHUNK;   // 782

    // workspace carve-up
    char* w = (char*)d_ws;
    size_t off = 0;
    auto alloc = [&](size_t bytes) { size_t r = off; off += (bytes + 255) & ~(size_t)255; return r; };
    size_t o_bcnt = alloc((size_t)NBUCK_C * 4);    // needs zero (coarse bucket cursor)
    size_t o_pool = alloc((size_t)NG * 4 * 4);     // needs zero (pooled z sums)
    size_t o_cnt  = alloc((size_t)NG * 4);         // needs zero
    size_t zero_bytes = off;
    size_t o_deg  = alloc((size_t)N * 4);
    size_t o_dinv = alloc((size_t)N * 4);
    size_t o_roff = alloc((size_t)N * 4);
    size_t o_xs   = alloc((size_t)N * 8 * 4);      // prescaled x (x*dinv), 2 float4/node
    size_t o_csrc = alloc((size_t)NBUCK_C * BCAP_C * 4);  // coarse-padded CSR adjacency (7.2 MB)
    size_t o_bin  = alloc((size_t)NBUCK_C * BCAP_C * 4);  // packed (src<<10)|dst_low (7.2 MB)
    size_t o_A1   = alloc((size_t)N * 16 * 2);     // layer-1 out fp16 (16 halfs/node)
    size_t o_A2   = alloc((size_t)N * 32 * 2);     // layer-2 out fp16 (32 halfs/node)
    size_t o_z    = alloc((size_t)N * 4 * 4);      // z projections (float4/node)
    size_t o_M    = alloc((size_t)64 * 4 * 4);     // W4@Wlin
    size_t o_bb   = alloc((size_t)4 * 4);          // b4@Wlin + blin
    (void)ws_size;
    int*      bcnt   = (int*)(w + o_bcnt);
    float*    pool   = (float*)(w + o_pool);
    float*    cnt    = (float*)(w + o_cnt);
    int*      deg    = (int*)(w + o_deg);
    float*    dinv   = (float*)(w + o_dinv);
    int*      roff   = (int*)(w + o_roff);
    float4*   xs     = (float4*)(w + o_xs);
    int*      csrc   = (int*)(w + o_csrc);
    unsigned* binned = (unsigned*)(w + o_bin);
    float2*   A1_2   = (float2*)(w + o_A1);
    float4*   A1     = (float4*)(w + o_A1);
    float4*   A2     = (float4*)(w + o_A2);
    float4*   z      = (float4*)(w + o_z);
    float*    M      = (float*)(w + o_M);
    float*    bb     = (float*)(w + o_bb);

    hipMemsetAsync(w, 0, zero_bytes, stream);

    // ---- head constants (independent; launch early) ----
    makeM_kernel<<<1, 256, 0, stream>>>(W4, b4, Wlin, blin, M, bb);

    // ---- CSR build: coarse bin (R18-verified) + whole-bucket build (98 x 1024) ----
    bin_kernel<<<NBIN, 256, 0, stream>>>(esrc, edst, bcnt, binned, E);
    build_csr_kernel<<<NBUCK_C, 1024, 0, stream>>>(binned, bcnt, (const float4*)x, xs,
                                                   deg, dinv, roff, csrc, N);

    // ---- layer 1 fused: agg(prescaled, 4 threads/node) + matmul(8->16) + prelu ----
    aggmm1_kernel<<<(N * 4 + 255) / 256, 256, 0, stream>>>(
        xs, roff, deg, dinv, csrc, W1, b1, a1, A1_2, N);

    // ---- layer 2 fused: agg16 (4 threads/node) + matmul(16->32) + prelu + dinv ----
    aggmm2_kernel<<<(N * 4 + 255) / 256, 256, 0, stream>>>(
        A1, roff, deg, dinv, csrc, W2, b2, a2, A2, N);

    // ---- layer 3 fused: agg32 (8 threads/node) + matmul(32->64) + prelu + dinv + @M -> z ----
    aggmm3_kernel<<<(N * 8 + 255) / 256, 256, 0, stream>>>(
        A2, roff, deg, dinv, csrc, W3, b3, a3, M, z, N);

    // ---- layer 4 in z-space: gather-aggregate (2 threads/node) + pool ----
    aggpool4_kernel<<<(N * 2 + 255) / 256, 256, 0, stream>>>(
        z, roff, deg, dinv, csrc, batch, pool, cnt, N);
    head_kernel<<<1, 256, 0, stream>>>(pool, cnt, bb, out);
}

// Round 25
// 222.698 us; speedup vs baseline: 1.0245x; 1.0245x over previous
//
#include <hip/hip_runtime.h>
#include <hip/hip_fp16.h>

// Problem constants (match reference file)
#define NN 100000
#define NE 1600000
#define NG 64

// dst-bucketing for the CSR build (single-level, verified config)
#define BSHIFT 7
#define BUCKW (1 << BSHIFT)                 // 128 nodes per bucket
#define NBUCK ((NN + BUCKW - 1) >> BSHIFT)  // 782
#define BCAP 2560                           // fixed per-bucket capacity (~11 sigma margin)
#define BIN_CHUNK 4096                      // 391 blocks (verified)

// ---- fp16 helpers (activations stored fp16, math in fp32) ----
union H8 { float4 f4; __half2 h2[4]; };
union H4 { float2 f2; __half2 h2[2]; };
__device__ __forceinline__ void h8_to_f(const H8& h, float* f) {
    float2 a = __half22float2(h.h2[0]);
    float2 b = __half22float2(h.h2[1]);
    float2 c = __half22float2(h.h2[2]);
    float2 d = __half22float2(h.h2[3]);
    f[0]=a.x; f[1]=a.y; f[2]=b.x; f[3]=b.y; f[4]=c.x; f[5]=c.y; f[6]=d.x; f[7]=d.y;
}
__device__ __forceinline__ H8 f_to_h8(const float* f) {
    H8 h;
    h.h2[0] = __floats2half2_rn(f[0], f[1]);
    h.h2[1] = __floats2half2_rn(f[2], f[3]);
    h.h2[2] = __floats2half2_rn(f[4], f[5]);
    h.h2[3] = __floats2half2_rn(f[6], f[7]);
    return h;
}
__device__ __forceinline__ float prelu_f(float x, float s) {
    return fmaxf(x, 0.f) + s * fminf(x, 0.f);
}

// ---------------- bin edges by dst-bucket into fixed-capacity slots ----------------
__global__ __launch_bounds__(256) void bin_kernel(const int* __restrict__ src,
                                                  const int* __restrict__ dst,
                                                  int* __restrict__ bcnt,
                                                  unsigned* __restrict__ binned, int E) {
    __shared__ int h[NBUCK];
    __shared__ int cur[NBUCK];
    for (int i = threadIdx.x; i < NBUCK; i += 256) h[i] = 0;
    __syncthreads();
    int base = blockIdx.x * BIN_CHUNK;
    int end = base + BIN_CHUNK; if (end > E) end = E;
    for (int e = base + threadIdx.x; e < end; e += 256)
        atomicAdd(&h[dst[e] >> BSHIFT], 1);
    __syncthreads();
    for (int i = threadIdx.x; i < NBUCK; i += 256) {
        int c = h[i];
        cur[i] = c ? (i * BCAP + atomicAdd(&bcnt[i], c)) : 0;  // reserve contiguous sub-range
    }
    __syncthreads();
    for (int e = base + threadIdx.x; e < end; e += 256) {
        unsigned s = (unsigned)src[e], d = (unsigned)dst[e];
        int pos = atomicAdd(&cur[d >> BSHIFT], 1);
        binned[pos] = (s << BSHIFT) | (d & (BUCKW - 1));
    }
}

// ======== fused CSR tail: deg + dinv + xs prescale + roff + csr_src placement ========
__global__ __launch_bounds__(256) void build_csr_kernel(
    const unsigned* __restrict__ binned, const int* __restrict__ bucket_cnt,
    const float4* __restrict__ x4, float4* __restrict__ xs,
    int* __restrict__ deg, float* __restrict__ dinv,
    int* __restrict__ roff, int* __restrict__ csr_src, int n) {
    __shared__ int ldeg[BUCKW];
    __shared__ int lscan[2][BUCKW];
    __shared__ int lcur[BUCKW];
    int b = blockIdx.x;
    int tid = threadIdx.x;
    for (int i = tid; i < BUCKW; i += 256) ldeg[i] = 0;
    __syncthreads();
    int start = b * BCAP, cnt = bucket_cnt[b];
    for (int k = tid; k < cnt; k += 256)
        atomicAdd(&ldeg[binned[start + k] & (BUCKW - 1)], 1);
    __syncthreads();
    if (tid < BUCKW) lscan[0][tid] = ldeg[tid];
    __syncthreads();
    int cur = 0;
    for (int off = 1; off < BUCKW; off <<= 1) {
        int x = 0;
        if (tid < BUCKW) {
            x = lscan[cur][tid];
            if (tid >= off) x += lscan[cur][tid - off];
        }
        __syncthreads();
        if (tid < BUCKW) lscan[cur ^ 1][tid] = x;
        __syncthreads();
        cur ^= 1;
    }
    int v0 = b << BSHIFT;
    if (tid < BUCKW) {
        int v = v0 + tid;
        if (v < n) {
            int dg = ldeg[tid];
            deg[v] = dg;
            float dv = rsqrtf((float)dg + 1.0f);  // +1 = self loop
            dinv[v] = dv;
            float4 h0 = x4[(size_t)v * 2 + 0];
            float4 h1 = x4[(size_t)v * 2 + 1];
            h0.x *= dv; h0.y *= dv; h0.z *= dv; h0.w *= dv;
            h1.x *= dv; h1.y *= dv; h1.z *= dv; h1.w *= dv;
            xs[(size_t)v * 2 + 0] = h0;
            xs[(size_t)v * 2 + 1] = h1;
            int r = start + lscan[cur][tid] - dg; // bucket-local exclusive prefix
            roff[v] = r;
            lcur[tid] = r;
        }
    }
    __syncthreads();
    for (int k = tid; k < cnt; k += 256) {
        unsigned e = binned[start + k];
        int pos = atomicAdd(&lcur[e & (BUCKW - 1)], 1);
        csr_src[pos] = (int)(e >> BSHIFT);
    }
}

// ---------------- makeM: M = W4 @ Wlin (64x4), bb = b4 @ Wlin + blin ----------------
__global__ __launch_bounds__(256) void makeM_kernel(
    const float* __restrict__ W4, const float* __restrict__ b4,
    const float* __restrict__ Wlin, const float* __restrict__ blin,
    float* __restrict__ M, float* __restrict__ bb) {
    int t = threadIdx.x;          // 256 = 64 * 4
    int k = t >> 2, c = t & 3;
    float m = 0.f;
    for (int j = 0; j < 128; ++j) m += W4[k * 128 + j] * Wlin[j * 4 + c];
    M[k * 4 + c] = m;
    if (t < 4) {
        float v = blin[t];
        for (int j = 0; j < 128; ++j) v += b4[j] * Wlin[j * 4 + t];
        bb[t] = v;
    }
}

// ======== LAYER 1 fused: agg(prescaled xs, neighbor-split x2) + matmul(8->16) =========
// 4 threads/node: c = input half (4 floats), h = neighbor half (combine via xor 2).
// Each thread computes 4 of 16 outputs (block h*2+c), written as one float2 (4 halfs).
__global__ __launch_bounds__(256) void aggmm1_kernel(
    const float4* __restrict__ xs, const int* __restrict__ row_off,
    const int* __restrict__ deg, const float* __restrict__ dinv,
    const int* __restrict__ csr_src, const float* __restrict__ W1,
    const float* __restrict__ b1, const float* __restrict__ a1,
    float2* __restrict__ Aout2, int n) {
    __shared__ float Wl[8 * 16];
    for (int i = threadIdx.x; i < 8 * 16; i += 256) Wl[i] = W1[i];
    __syncthreads();
    int idx = blockIdx.x * 256 + threadIdx.x;
    if (idx >= n * 4) return;                 // 4-lane groups aligned
    int v = idx >> 2;
    int c = idx & 1;
    int h = (idx >> 1) & 1;
    float4 acc = (h == 0) ? xs[(size_t)v * 2 + c] : make_float4(0.f, 0.f, 0.f, 0.f);
    int start = row_off[v], cnt = deg[v];
    int mid = cnt >> 1;
    int beg = h ? mid : 0;
    int myend = h ? cnt : mid;
    const int* __restrict__ row = csr_src + start;
    int j = beg;
    for (; j + 4 <= myend; j += 4) {
        int s0 = row[j], s1 = row[j + 1], s2 = row[j + 2], s3 = row[j + 3];
        float4 a0 = xs[(size_t)s0 * 2 + c];
        float4 a1v = xs[(size_t)s1 * 2 + c];
        float4 a2 = xs[(size_t)s2 * 2 + c];
        float4 a3 = xs[(size_t)s3 * 2 + c];
        acc.x += (a0.x + a1v.x) + (a2.x + a3.x);
        acc.y += (a0.y + a1v.y) + (a2.y + a3.y);
        acc.z += (a0.z + a1v.z) + (a2.z + a3.z);
        acc.w += (a0.w + a1v.w) + (a2.w + a3.w);
    }
    for (; j < myend; ++j) {
        int s = row[j];
        float4 a = xs[(size_t)s * 2 + c];
        acc.x += a.x; acc.y += a.y; acc.z += a.z; acc.w += a.w;
    }
    acc.x += __shfl_xor(acc.x, 2, 64);        // combine h-halves
    acc.y += __shfl_xor(acc.y, 2, 64);
    acc.z += __shfl_xor(acc.z, 2, 64);
    acc.w += __shfl_xor(acc.w, 2, 64);
    float dvv = dinv[v];
    float t[4] = { acc.x * dvv, acc.y * dvv, acc.z * dvv, acc.w * dvv };
    float po[4];
#pragma unroll
    for (int k = 0; k < 4; ++k) po[k] = __shfl_xor(t[k], 1, 64);   // c-partner inputs
    int ow = (h * 2 + c) * 4;                 // this thread's 4-output block
    int e0 = c * 4, e1 = 4 - e0;
    float accm[4];
#pragma unroll
    for (int q = 0; q < 4; ++q) accm[q] = b1[ow + q];
#pragma unroll
    for (int k = 0; k < 4; ++k) {
        float r1 = t[k], r2 = po[k];
        const float* w1 = &Wl[(e0 + k) * 16 + ow];
        const float* w2 = &Wl[(e1 + k) * 16 + ow];
#pragma unroll
        for (int q = 0; q < 4; ++q) accm[q] += r1 * w1[q] + r2 * w2[q];
    }
    float s = *a1;
    float o[4];
#pragma unroll
    for (int q = 0; q < 4; ++q) o[q] = prelu_f(accm[q], s) * dvv;
    H4 ho;
    ho.h2[0] = __floats2half2_rn(o[0], o[1]);
    ho.h2[1] = __floats2half2_rn(o[2], o[3]);
    Aout2[(size_t)v * 4 + (h * 2 + c)] = ho.f2;   // A-row = 16 halfs = 4 float2s
}

// ======== LAYER 2 fused: agg(16, neighbor-split x2) + matmul(16->32) + prelu ==========
__global__ __launch_bounds__(256) void aggmm2_kernel(
    const float4* __restrict__ hs, const int* __restrict__ row_off,
    const int* __restrict__ deg, const float* __restrict__ dinv,
    const int* __restrict__ csr_src, const float* __restrict__ W2,
    const float* __restrict__ b2, const float* __restrict__ a2,
    float4* __restrict__ Aout, int n) {
    __shared__ float Wl[16 * 32];   // 2 KB
    for (int i = threadIdx.x; i < 16 * 32; i += 256) Wl[i] = W2[i];
    __syncthreads();
    int idx = blockIdx.x * 256 + threadIdx.x;
    if (idx >= n * 4) return;                 // 4-lane groups aligned: partners agree
    int v = idx >> 2;
    int c = idx & 1;
    int h = (idx >> 1) & 1;
    float a[8];
    if (h == 0) { H8 t; t.f4 = hs[(size_t)v * 2 + c]; h8_to_f(t, a); }
    else {
#pragma unroll
        for (int k = 0; k < 8; ++k) a[k] = 0.f;
    }
    int start = row_off[v], cnt = deg[v];
    int mid = cnt >> 1;
    int beg = h ? mid : 0;
    int myend = h ? cnt : mid;
    const int* __restrict__ row = csr_src + start;
    int j = beg;
    for (; j + 4 <= myend; j += 4) {
        H8 hh[4];
#pragma unroll
        for (int q = 0; q < 4; ++q) hh[q].f4 = hs[(size_t)row[j + q] * 2 + c];
#pragma unroll
        for (int q = 0; q < 4; ++q) {
            float f[8]; h8_to_f(hh[q], f);
#pragma unroll
            for (int k = 0; k < 8; ++k) a[k] += f[k];
        }
    }
    for (; j < myend; ++j) {
        H8 t; t.f4 = hs[(size_t)row[j] * 2 + c];
        float f[8]; h8_to_f(t, f);
#pragma unroll
        for (int k = 0; k < 8; ++k) a[k] += f[k];
    }
#pragma unroll
    for (int k = 0; k < 8; ++k) a[k] += __shfl_xor(a[k], 2, 64);   // combine h-halves
    float dvv = dinv[v];
#pragma unroll
    for (int k = 0; k < 8; ++k) a[k] *= dvv;
    float pa[8];
#pragma unroll
    for (int k = 0; k < 8; ++k) pa[k] = __shfl_xor(a[k], 1, 64);   // c-partner inputs
    int ow = (h * 2 + c) * 8;                 // this thread's 8-output block
    int e0 = c * 8, e1 = 8 - e0;
    float accm[8];
#pragma unroll
    for (int q = 0; q < 8; ++q) accm[q] = b2[ow + q];
#pragma unroll
    for (int k = 0; k < 8; ++k) {
        float r1 = a[k], r2 = pa[k];
        const float* w1 = &Wl[(e0 + k) * 32 + ow];
        const float* w2 = &Wl[(e1 + k) * 32 + ow];
#pragma unroll
        for (int q = 0; q < 8; ++q) accm[q] += r1 * w1[q] + r2 * w2[q];
    }
    float s = *a2;
    float o[8];
#pragma unroll
    for (int q = 0; q < 8; ++q) o[q] = prelu_f(accm[q], s) * dvv;
    H8 ho = f_to_h8(o);
    Aout[(size_t)v * 4 + (h * 2 + c)] = ho.f4;   // A-row = 32 halfs = 4 float4s
}

// ======== LAYER 3 fused: agg(32, neighbor-split x2) + matmul(32->64) + @M -> z ========
__global__ __launch_bounds__(256) void aggmm3_kernel(
    const float4* __restrict__ hs, const int* __restrict__ row_off,
    const int* __restrict__ deg, const float* __restrict__ dinv,
    const int* __restrict__ csr_src, const float* __restrict__ W3,
    const float* __restrict__ b3, const float* __restrict__ a3,
    const float* __restrict__ M, float4* __restrict__ z, int n) {
    __shared__ float Wl[32 * 64];   // 8 KB
    __shared__ float Ml[64 * 4];    // 1 KB
    for (int i = threadIdx.x; i < 32 * 64; i += 256) Wl[i] = W3[i];
    for (int i = threadIdx.x; i < 64 * 4; i += 256) Ml[i] = M[i];
    __syncthreads();
    int idx = blockIdx.x * 256 + threadIdx.x;
    if (idx >= n * 8) return;                 // 8-lane groups aligned
    int v = idx >> 3;
    int c = idx & 3;
    int h = (idx >> 2) & 1;
    float a[8];
    if (h == 0) { H8 t; t.f4 = hs[(size_t)v * 4 + c]; h8_to_f(t, a); }
    else {
#pragma unroll
        for (int k = 0; k < 8; ++k) a[k] = 0.f;
    }
    int start = row_off[v], cnt = deg[v];
    int mid = cnt >> 1;
    int beg = h ? mid : 0;
    int myend = h ? cnt : mid;
    const int* __restrict__ row = csr_src + start;
    int j = beg;
    for (; j + 4 <= myend; j += 4) {
        H8 hh[4];
#pragma unroll
        for (int q = 0; q < 4; ++q) hh[q].f4 = hs[(size_t)row[j + q] * 4 + c];
#pragma unroll
        for (int q = 0; q < 4; ++q) {
            float f[8]; h8_to_f(hh[q], f);
#pragma unroll
            for (int k = 0; k < 8; ++k) a[k] += f[k];
        }
    }
    for (; j < myend; ++j) {
        H8 t; t.f4 = hs[(size_t)row[j] * 4 + c];
        float f[8]; h8_to_f(t, f);
#pragma unroll
        for (int k = 0; k < 8; ++k) a[k] += f[k];
    }
#pragma unroll
    for (int k = 0; k < 8; ++k) a[k] += __shfl_xor(a[k], 4, 64);   // combine h-halves
    float dvv = dinv[v];
#pragma unroll
    for (int k = 0; k < 8; ++k) a[k] *= dvv;
    int ow = (h * 4 + c) * 8;                 // this thread's 8-output block
    float accm[8];
#pragma unroll
    for (int q = 0; q < 8; ++q) accm[q] = b3[ow + q];
#pragma unroll
    for (int m = 0; m < 4; ++m) {
        float cur[8];
        if (m == 0) {
#pragma unroll
            for (int k = 0; k < 8; ++k) cur[k] = a[k];
        } else {
#pragma unroll
            for (int k = 0; k < 8; ++k) cur[k] = __shfl_xor(a[k], m, 64);
        }
        int eb = (c ^ m) * 8;
#pragma unroll
        for (int k = 0; k < 8; ++k) {
            float rk = cur[k];
            const float* wp = &Wl[(eb + k) * 64 + ow];
#pragma unroll
            for (int q = 0; q < 8; ++q) accm[q] += rk * wp[q];
        }
    }
    float s = *a3;
    float px = 0.f, py = 0.f, pz = 0.f, pw = 0.f;
#pragma unroll
    for (int q = 0; q < 8; ++q) {
        float o = prelu_f(accm[q], s) * dvv;
        const float* mp = &Ml[(ow + q) * 4];
        px += o * mp[0]; py += o * mp[1]; pz += o * mp[2]; pw += o * mp[3];
    }
#pragma unroll
    for (int mask = 1; mask <= 4; mask <<= 1) {
        px += __shfl_xor(px, mask, 64);
        py += __shfl_xor(py, mask, 64);
        pz += __shfl_xor(pz, mask, 64);
        pw += __shfl_xor(pw, mask, 64);
    }
    if ((idx & 7) == 0) z[v] = make_float4(px, py, pz, pw);
}

// ===== layer-4 aggregation + pooling in z-space (neighbor-split x2, wave-reduced) =====
__global__ __launch_bounds__(256) void aggpool4_kernel(
    const float4* __restrict__ z, const int* __restrict__ row_off,
    const int* __restrict__ deg, const float* __restrict__ dinv,
    const int* __restrict__ csr_src, const int* __restrict__ batch,
    float* __restrict__ sums, float* __restrict__ cnt, int n) {
    __shared__ float lacc[NG * 4];
    __shared__ float lcnt[NG];
    int tid = threadIdx.x;
    if (tid < NG * 4) lacc[tid] = 0.f;
    if (tid < NG) lcnt[tid] = 0.f;
    __syncthreads();
    int idx = blockIdx.x * 256 + tid;
    bool valid = (idx < n * 2);
    int v = idx >> 1;
    int h = idx & 1;
    float cx = 0.f, cy = 0.f, cz = 0.f, cw = 0.f, rc = 0.f;
    int g = -1;
    if (valid) {
        float4 acc = (h == 0) ? z[v] : make_float4(0.f, 0.f, 0.f, 0.f);
        int start = row_off[v], dcnt = deg[v];
        int mid = dcnt >> 1;
        int beg = h ? mid : 0;
        int myend = h ? dcnt : mid;
        const int* __restrict__ row = csr_src + start;
        int j = beg;
        for (; j + 4 <= myend; j += 4) {
            float4 a0 = z[row[j]];
            float4 a1 = z[row[j + 1]];
            float4 a2 = z[row[j + 2]];
            float4 a3 = z[row[j + 3]];
            acc.x += (a0.x + a1.x) + (a2.x + a3.x);
            acc.y += (a0.y + a1.y) + (a2.y + a3.y);
            acc.z += (a0.z + a1.z) + (a2.z + a3.z);
            acc.w += (a0.w + a1.w) + (a2.w + a3.w);
        }
        for (; j < myend; ++j) {
            float4 a = z[row[j]];
            acc.x += a.x; acc.y += a.y; acc.z += a.z; acc.w += a.w;
        }
        cx = acc.x; cy = acc.y; cz = acc.z; cw = acc.w;
        g = batch[v];
    }
    cx += __shfl_xor(cx, 1, 64);              // combine h-halves (pairs aligned)
    cy += __shfl_xor(cy, 1, 64);
    cz += __shfl_xor(cz, 1, 64);
    cw += __shfl_xor(cw, 1, 64);
    if (valid) {
        float dv = dinv[v];
        cx *= dv; cy *= dv; cz *= dv; cw *= dv;
    }
    if (!valid || h == 1) { cx = cy = cz = cw = 0.f; rc = 0.f; }
    else rc = 1.f;
    int g0 = __shfl(g, 0, 64);
    if (__all(g == g0 || !valid)) {
#pragma unroll
        for (int mask = 32; mask >= 1; mask >>= 1) {
            cx += __shfl_xor(cx, mask, 64);
            cy += __shfl_xor(cy, mask, 64);
            cz += __shfl_xor(cz, mask, 64);
            cw += __shfl_xor(cw, mask, 64);
            rc += __shfl_xor(rc, mask, 64);
        }
        if ((tid & 63) == 0 && g0 >= 0) {
            float* lp = &lacc[g0 * 4];
            atomicAdd(lp + 0, cx); atomicAdd(lp + 1, cy);
            atomicAdd(lp + 2, cz); atomicAdd(lp + 3, cw);
            atomicAdd(&lcnt[g0], rc);
        }
    } else if (valid && h == 0) {
        float* lp = &lacc[g * 4];
        atomicAdd(lp + 0, cx); atomicAdd(lp + 1, cy);
        atomicAdd(lp + 2, cz); atomicAdd(lp + 3, cw);
        atomicAdd(&lcnt[g], 1.f);
    }
    __syncthreads();
    if (tid < NG * 4) {
        float val = lacc[tid];
        if (val != 0.f) atomicAdd(&sums[tid], val);
    }
    if (tid < NG) {
        float val = lcnt[tid];
        if (val != 0.f) atomicAdd(&cnt[tid], val);
    }
}

// ---------------- head: out[g][c] = sums[g][c]/cnt[g] + bb[c] ----------------
__global__ void head_kernel(const float* __restrict__ sums, const float* __restrict__ cnt,
                            const float* __restrict__ bb, float* __restrict__ out) {
    int t = threadIdx.x;          // 256 = 64 graphs * 4 classes
    int g = t >> 2, c = t & 3;
    out[t] = sums[t] / fmaxf(cnt[g], 1.f) + bb[c];
}

extern "C" void kernel_launch(void* const* d_in, const int* in_sizes, int n_in,
                              void* d_out, int out_size, void* d_ws, size_t ws_size,
                              hipStream_t stream) {
    const float* x    = (const float*)d_in[0];
    const int* esrc   = (const int*)d_in[1];
    const int* edst   = (const int*)d_in[2];
    const int* batch  = (const int*)d_in[3];
    const float* W1 = (const float*)d_in[4],  *b1 = (const float*)d_in[5];
    const float* W2 = (const float*)d_in[6],  *b2 = (const float*)d_in[7];
    const float* W3 = (const float*)d_in[8],  *b3 = (const float*)d_in[9];
    const float* W4 = (const float*)d_in[10], *b4 = (const float*)d_in[11];
    const float* a1 = (const float*)d_in[12];
    const float* a2 = (const float*)d_in[13];
    const float* a3 = (const float*)d_in[14];
    const float* Wlin = (const float*)d_in[15], *blin = (const float*)d_in[16];
    float* out = (float*)d_out;

    const int N = NN, E = NE;
    const int NBIN = (E + BIN_CHUNK - 1) / BIN_CHUNK;   // 391

    // workspace carve-up
    char* w = (char*)d_ws;
    size_t off = 0;
    auto alloc = [&](size_t bytes) { size_t r = off; off += (bytes + 255) & ~(size_t)255; return r; };
    size_t o_bcnt = alloc((size_t)NBUCK * 4);      // needs zero (per-bucket cursor)
    size_t o_pool = alloc((size_t)NG * 4 * 4);     // needs zero (pooled z sums)
    size_t o_cnt  = alloc((size_t)NG * 4);         // needs zero
    size_t zero_bytes = off;
    size_t o_deg  = alloc((size_t)N * 4);
    size_t o_dinv = alloc((size_t)N * 4);
    size_t o_roff = alloc((size_t)N * 4);
    size_t o_xs   = alloc((size_t)N * 8 * 4);      // prescaled x (x*dinv), 2 float4/node
    size_t o_csrc = alloc((size_t)NBUCK * BCAP * 4);  // bucket-padded CSR adjacency
    size_t o_bin  = alloc((size_t)NBUCK * BCAP * 4);  // packed (src<<7)|dst_low, bucket-padded
    size_t o_A1   = alloc((size_t)N * 16 * 2);     // layer-1 out fp16 (16 halfs/node)
    size_t o_A2   = alloc((size_t)N * 32 * 2);     // layer-2 out fp16 (32 halfs/node)
    size_t o_z    = alloc((size_t)N * 4 * 4);      // z projections (float4/node)
    size_t o_M    = alloc((size_t)64 * 4 * 4);     // W4@Wlin
    size_t o_bb   = alloc((size_t)4 * 4);          // b4@Wlin + blin
    (void)ws_size;
    int*      bcnt   = (int*)(w + o_bcnt);
    float*    pool   = (float*)(w + o_pool);
    float*    cnt    = (float*)(w + o_cnt);
    int*      deg    = (int*)(w + o_deg);
    float*    dinv   = (float*)(w + o_dinv);
    int*      roff   = (int*)(w + o_roff);
    float4*   xs     = (float4*)(w + o_xs);
    int*      csrc   = (int*)(w + o_csrc);
    unsigned* binned = (unsigned*)(w + o_bin);
    float2*   A1_2   = (float2*)(w + o_A1);
    float4*   A1     = (float4*)(w + o_A1);
    float4*   A2     = (float4*)(w + o_A2);
    float4*   z      = (float4*)(w + o_z);
    float*    M      = (float*)(w + o_M);
    float*    bb     = (float*)(w + o_bb);

    hipMemsetAsync(w, 0, zero_bytes, stream);

    // ---- head constants (independent; launch early) ----
    makeM_kernel<<<1, 256, 0, stream>>>(W4, b4, Wlin, blin, M, bb);

    // ---- CSR build via fixed-capacity dst-bucket binning (verified config) ----
    bin_kernel<<<NBIN, 256, 0, stream>>>(esrc, edst, bcnt, binned, E);
    build_csr_kernel<<<NBUCK, 256, 0, stream>>>(binned, bcnt, (const float4*)x, xs,
                                                deg, dinv, roff, csrc, N);

    // ---- layer 1 fused: agg(prescaled, 4 threads/node) + matmul(8->16) + prelu ----
    aggmm1_kernel<<<(N * 4 + 255) / 256, 256, 0, stream>>>(
        xs, roff, deg, dinv, csrc, W1, b1, a1, A1_2, N);

    // ---- layer 2 fused: agg16 (4 threads/node) + matmul(16->32) + prelu + dinv ----
    aggmm2_kernel<<<(N * 4 + 255) / 256, 256, 0, stream>>>(
        A1, roff, deg, dinv, csrc, W2, b2, a2, A2, N);

    // ---- layer 3 fused: agg32 (8 threads/node) + matmul(32->64) + prelu + dinv + @M -> z ----
    aggmm3_kernel<<<(N * 8 + 255) / 256, 256, 0, stream>>>(
        A2, roff, deg, dinv, csrc, W3, b3, a3, M, z, N);

    // ---- layer 4 in z-space: gather-aggregate (2 threads/node) + pool ----
    aggpool4_kernel<<<(N * 2 + 255) / 256, 256, 0, stream>>>(
        z, roff, deg, dinv, csrc, batch, pool, cnt, N);
    head_kernel<<<1, 256, 0, stream>>>(pool, cnt, bb, out);
}